// Round 3
// baseline (3642.848 us; speedup 1.0000x reference)
//
#include <hip/hip_runtime.h>

// TemporalCausalMaps on MI355X (gfx950), round 6.
// Back to ONE wave per block (round-5's 2-wave barriers regressed).
// Key restructure: n-outer / idx-inner (legal: cell (idx,n) depends only on
// (idx-1,n) and (idx,n-1)). Per-node weights become reusable across the 8
// idx iterations:
//  - resident in VGPRs across the idx loop: gru_whh (both layers, half-split,
//    18 float4) + cm_w2 row (16 float4).
//  - prefetched per idx, issue placed phases before use: gru_wih (12 float4,
//    L0 issued before proj, L1 issued before rec-L0), cm_w1 (6 float4,
//    issued before rec-L1).
// Cond-net computed ONCE per decoded row (at end of cell) into an LDS emb
// history (ping-pong per node); stage-1 self/pred embeddings become pure
// LDS reads. Halves cond FLOPs and removes cross-node recompute.

#define NT 64

__device__ __forceinline__ float sigm(float x) { return 1.0f / (1.0f + __expf(-x)); }
__device__ __forceinline__ float tanh_fast(float x) {
  x = fminf(15.0f, fmaxf(-15.0f, x));
  float e = __expf(2.0f * x);
  return (e - 1.0f) / (e + 1.0f);
}
__device__ __forceinline__ float leaky(float x) { return x >= 0.0f ? x : 0.01f * x; }

template <int N4>
__device__ __forceinline__ float dotv(const float* __restrict__ w, const float* h) {
  const float4* w4 = reinterpret_cast<const float4*>(w);
  const float4* h4 = reinterpret_cast<const float4*>(h);
  float acc = 0.0f;
#pragma unroll
  for (int i = 0; i < N4; ++i) {
    float4 a = w4[i], b = h4[i];
    acc = fmaf(a.x, b.x, acc); acc = fmaf(a.y, b.y, acc);
    acc = fmaf(a.z, b.z, acc); acc = fmaf(a.w, b.w, acc);
  }
  return acc;
}

// 24-wide dot against a register float4[6] row, LDS activation base.
#define DOT24(ACC, W, P)                                              \
  {                                                                   \
    const float4* h4_ = reinterpret_cast<const float4*>(P);           \
    for (int i_ = 0; i_ < 6; ++i_) {                                  \
      float4 hh_ = h4_[i_];                                           \
      ACC = fmaf(W[i_].x, hh_.x, ACC); ACC = fmaf(W[i_].y, hh_.y, ACC); \
      ACC = fmaf(W[i_].z, hh_.z, ACC); ACC = fmaf(W[i_].w, hh_.w, ACC); \
    }                                                                 \
  }

// LDS layout (floats), 16B-aligned segment starts. Total 4000 floats = 16000 B.
//  s_x    [8][48]      @0      s_h   [8][24] @384    s_g  [8][24] @576
//  s_gi   [8][72]      @768    s_y   [8][24] @1344   s_hid [2][24] @1536
//  s_d1   [8][68]      @1584   s_d2  [8][68] @2128   s_dd [8]+pad  @2672
//  s_ch   [8][36]      @2688   s_hist[2][8][8][8]    @2976
__global__ __launch_bounds__(NT, 2) void tcm_kernel(
    const float* __restrict__ z,
    const float* __restrict__ cond_w1, const float* __restrict__ cond_b1,
    const float* __restrict__ cond_w2, const float* __restrict__ cond_b2,
    const float* __restrict__ proj_w, const float* __restrict__ proj_b,
    const float* __restrict__ gpw, const float* __restrict__ gpb,
    const float* __restrict__ gru_wih, const float* __restrict__ gru_whh,
    const float* __restrict__ gru_bih, const float* __restrict__ gru_bhh,
    const float* __restrict__ cm_w1, const float* __restrict__ cm_b1,
    const float* __restrict__ cm_w2, const float* __restrict__ cm_b2,
    const float* __restrict__ cm_w3, const float* __restrict__ cm_b3,
    const int* __restrict__ endw,
    float* __restrict__ out, int Btot) {
  __shared__ __align__(16) float lds[4000];
  float* s_x    = lds;
  float* s_h    = lds + 384;
  float* s_g    = lds + 576;
  float* s_gi   = lds + 768;
  float* s_y    = lds + 1344;
  float* s_hid  = lds + 1536;
  float* s_d1   = lds + 1584;   // stride 68
  float* s_d2   = lds + 2128;   // stride 68
  float* s_dd   = lds + 2672;   // 8 + 8 pad
  float* s_ch   = lds + 2688;   // stride 36
  float* s_hist = lds + 2976;   // [buf][idx][t][c] = buf*512 + idx*64 + t*8 + c

  const int lane = threadIdx.x;
  const int b = blockIdx.x;
  const int T = endw[0];

  const int jm = lane & 31;
  const int half = lane >> 5;
  const int jq = jm < 24 ? jm : 0;       // clamp for inactive lanes
  const int rowB = 64 + (lane & 7);

#pragma unroll 1
  for (int n = 0; n < 8; ++n) {
    // ---- resident per-node weights (loaded once, reused across 8 idx iters)
    float4 Wr0[3], Wz0[3], Wn0[3], Wr1[3], Wz1[3], Wn1[3];
    float bR0, bZ0, bN0, bR1, bZ1, bN1;
    {
      const float* whh0 = gru_whh + (size_t)(n * 2) * 72 * 24;
      const float* bhh0 = gru_bhh + (n * 2) * 72;
      const float4* wr = reinterpret_cast<const float4*>(whh0 + jq * 24 + half * 12);
      const float4* wz = reinterpret_cast<const float4*>(whh0 + (24 + jq) * 24 + half * 12);
      const float4* wn = reinterpret_cast<const float4*>(whh0 + (48 + jq) * 24 + half * 12);
      for (int i = 0; i < 3; ++i) { Wr0[i] = wr[i]; Wz0[i] = wz[i]; Wn0[i] = wn[i]; }
      bR0 = half ? 0.0f : bhh0[jq];
      bZ0 = half ? 0.0f : bhh0[24 + jq];
      bN0 = half ? 0.0f : bhh0[48 + jq];
      const float* whh1 = whh0 + 72 * 24;
      const float* bhh1 = bhh0 + 72;
      const float4* wr1 = reinterpret_cast<const float4*>(whh1 + jq * 24 + half * 12);
      const float4* wz1 = reinterpret_cast<const float4*>(whh1 + (24 + jq) * 24 + half * 12);
      const float4* wn1 = reinterpret_cast<const float4*>(whh1 + (48 + jq) * 24 + half * 12);
      for (int i = 0; i < 3; ++i) { Wr1[i] = wr1[i]; Wz1[i] = wz1[i]; Wn1[i] = wn1[i]; }
      bR1 = half ? 0.0f : bhh1[jq];
      bZ1 = half ? 0.0f : bhh1[24 + jq];
      bN1 = half ? 0.0f : bhh1[48 + jq];
    }
    float4 C2[16];
    {
      const float4* p = reinterpret_cast<const float4*>(cm_w2 + (size_t)(n * 64 + lane) * 64);
      for (int i = 0; i < 16; ++i) C2[i] = p[i];
    }
    const float c2b = cm_b2[n * 64 + lane];
    const float c1b = cm_b1[n * 64 + lane];

    float* hist_own = s_hist + (n & 1) * 512;
    float* hist_prd = s_hist + ((n & 1) ^ 1) * 512;

    const float* wih0 = gru_wih + (size_t)(n * 2) * 72 * 24;
    const float* wih1 = wih0 + 72 * 24;
    const float* bih0 = gru_bih + (n * 2) * 72;
    const float* bih1 = bih0 + 72;
    const float* zbase = z + ((size_t)n * Btot + b) * 8 * 32;

#pragma unroll 1
    for (int idx = 0; idx < T; ++idx) {
      const int L = idx + 1;
      // prefetch layer-0 input-gate rows (used 3 phases later)
      float4 WA[6], WB[6];
      float bA, bB;
      {
        const float4* wa = reinterpret_cast<const float4*>(wih0 + (size_t)lane * 24);
        const float4* wb = reinterpret_cast<const float4*>(wih0 + (size_t)rowB * 24);
        for (int i = 0; i < 6; ++i) { WA[i] = wa[i]; WB[i] = wb[i]; }
        bA = bih0[lane]; bB = bih0[rowB];
      }
      // ---- phase A: assemble s_x = [z | emb_self | emb_pred]
      if (lane < L * 8) {
        const float4* z4 = reinterpret_cast<const float4*>(zbase);
        int t = lane >> 3, q = lane & 7;
        reinterpret_cast<float4*>(s_x)[t * 12 + q] = z4[t * 8 + q];
      }
#pragma unroll 1
      for (int it = lane; it < L * 16; it += NT) {
        int t = it >> 4, c = it & 15;
        float v = 0.0f;
        if (c < 8) {
          if (t < idx) v = hist_own[(idx - 1) * 64 + t * 8 + c];
        } else {
          if (n > 0 && idx > 0) v = hist_prd[idx * 64 + t * 8 + (c - 8)];
        }
        s_x[t * 48 + 32 + c] = v;
      }
      __syncthreads();
      // ---- proj -> leaky
#pragma unroll 1
      for (int it = lane; it < L * 24; it += NT) {
        int t = it / 24, j = it - t * 24;
        float acc = proj_b[n * 24 + j] +
                    dotv<12>(proj_w + (size_t)(n * 24 + j) * 48, s_x + t * 48);
        s_h[t * 24 + j] = leaky(acc);
      }
      __syncthreads();
      // ---- gru_proj
#pragma unroll 1
      for (int it = lane; it < L * 24; it += NT) {
        int t = it / 24, j = it - t * 24;
        s_g[t * 24 + j] = gpb[j] + dotv<6>(gpw + j * 24, s_h + t * 24);
      }
      __syncthreads();
      // ---- gates L0 (src = s_g)
#pragma unroll 1
      for (int t = 0; t < L; ++t) {
        float accA = bA, accB = bB;
        DOT24(accA, WA, s_g + t * 24);
        DOT24(accB, WB, s_g + t * 24);
        s_gi[t * 72 + lane] = accA;
        if (lane < 8) s_gi[t * 72 + 64 + lane] = accB;
      }
      __syncthreads();
      // prefetch layer-1 input-gate rows (hidden under rec L0)
      {
        const float4* wa = reinterpret_cast<const float4*>(wih1 + (size_t)lane * 24);
        const float4* wb = reinterpret_cast<const float4*>(wih1 + (size_t)rowB * 24);
        for (int i = 0; i < 6; ++i) { WA[i] = wa[i]; WB[i] = wb[i]; }
        bA = bih1[lane]; bB = bih1[rowB];
      }
      // ---- rec L0 -> s_y (half-split, single-wave, no inner barriers)
      {
        if (lane < 24) s_hid[lane] = 0.0f;
        int cur = 0;
#pragma unroll 1
        for (int t = 0; t < L; ++t) {
          const float4* hp = reinterpret_cast<const float4*>(s_hid + cur * 24 + half * 12);
          float gr = bR0, gz = bZ0, gn = bN0;
          for (int i = 0; i < 3; ++i) {
            float4 hh = hp[i];
            gr = fmaf(Wr0[i].x, hh.x, gr); gr = fmaf(Wr0[i].y, hh.y, gr);
            gr = fmaf(Wr0[i].z, hh.z, gr); gr = fmaf(Wr0[i].w, hh.w, gr);
            gz = fmaf(Wz0[i].x, hh.x, gz); gz = fmaf(Wz0[i].y, hh.y, gz);
            gz = fmaf(Wz0[i].z, hh.z, gz); gz = fmaf(Wz0[i].w, hh.w, gz);
            gn = fmaf(Wn0[i].x, hh.x, gn); gn = fmaf(Wn0[i].y, hh.y, gn);
            gn = fmaf(Wn0[i].z, hh.z, gn); gn = fmaf(Wn0[i].w, hh.w, gn);
          }
          gr += __shfl_xor(gr, 32);
          gz += __shfl_xor(gz, 32);
          gn += __shfl_xor(gn, 32);
          const float* gi = s_gi + t * 72;
          float r   = sigm(gi[jq] + gr);
          float zg  = sigm(gi[24 + jq] + gz);
          float nn2 = tanh_fast(gi[48 + jq] + r * gn);
          float hold = s_hid[cur * 24 + jq];
          float hnew = fmaf(zg, hold - nn2, nn2);
          if (lane < 24) {
            s_hid[(cur ^ 1) * 24 + lane] = hnew;
            s_y[t * 24 + lane] = hnew;
          }
          cur ^= 1;
        }
      }
      __syncthreads();
      // ---- gates L1 (src = s_y)
#pragma unroll 1
      for (int t = 0; t < L; ++t) {
        float accA = bA, accB = bB;
        DOT24(accA, WA, s_y + t * 24);
        DOT24(accB, WB, s_y + t * 24);
        s_gi[t * 72 + lane] = accA;
        if (lane < 8) s_gi[t * 72 + 64 + lane] = accB;
      }
      __syncthreads();
      // prefetch cm1 row (hidden under rec L1)
      float4 C1[6];
      {
        const float4* p = reinterpret_cast<const float4*>(cm_w1 + (size_t)(n * 64 + lane) * 24);
        for (int i = 0; i < 6; ++i) C1[i] = p[i];
      }
      // ---- rec L1 -> s_y
      {
        if (lane < 24) s_hid[lane] = 0.0f;
        int cur = 0;
#pragma unroll 1
        for (int t = 0; t < L; ++t) {
          const float4* hp = reinterpret_cast<const float4*>(s_hid + cur * 24 + half * 12);
          float gr = bR1, gz = bZ1, gn = bN1;
          for (int i = 0; i < 3; ++i) {
            float4 hh = hp[i];
            gr = fmaf(Wr1[i].x, hh.x, gr); gr = fmaf(Wr1[i].y, hh.y, gr);
            gr = fmaf(Wr1[i].z, hh.z, gr); gr = fmaf(Wr1[i].w, hh.w, gr);
            gz = fmaf(Wz1[i].x, hh.x, gz); gz = fmaf(Wz1[i].y, hh.y, gz);
            gz = fmaf(Wz1[i].z, hh.z, gz); gz = fmaf(Wz1[i].w, hh.w, gz);
            gn = fmaf(Wn1[i].x, hh.x, gn); gn = fmaf(Wn1[i].y, hh.y, gn);
            gn = fmaf(Wn1[i].w, hh.w, gn); gn = fmaf(Wn1[i].z, hh.z, gn);
          }
          gr += __shfl_xor(gr, 32);
          gz += __shfl_xor(gz, 32);
          gn += __shfl_xor(gn, 32);
          const float* gi = s_gi + t * 72;
          float r   = sigm(gi[jq] + gr);
          float zg  = sigm(gi[24 + jq] + gz);
          float nn2 = tanh_fast(gi[48 + jq] + r * gn);
          float hold = s_hid[cur * 24 + jq];
          float hnew = fmaf(zg, hold - nn2, nn2);
          if (lane < 24) {
            s_hid[(cur ^ 1) * 24 + lane] = hnew;
            s_y[t * 24 + lane] = hnew;
          }
          cur ^= 1;
        }
      }
      __syncthreads();
      // ---- cm1 (resident-per-idx C1)
#pragma unroll 1
      for (int t = 0; t < L; ++t) {
        float acc = c1b;
        DOT24(acc, C1, s_y + t * 24);
        s_d1[t * 68 + lane] = fmaxf(acc, 0.0f);
      }
      __syncthreads();
      // ---- cm2 (resident C2)
#pragma unroll 1
      for (int t = 0; t < L; ++t) {
        const float4* d4 = reinterpret_cast<const float4*>(s_d1 + t * 68);
        float acc = c2b;
        for (int i = 0; i < 16; ++i) {
          float4 hh = d4[i];
          acc = fmaf(C2[i].x, hh.x, acc); acc = fmaf(C2[i].y, hh.y, acc);
          acc = fmaf(C2[i].z, hh.z, acc); acc = fmaf(C2[i].w, hh.w, acc);
        }
        s_d2[t * 68 + lane] = fmaxf(acc, 0.0f);
      }
      __syncthreads();
      // ---- cm3 -> decoded + emit
      if (lane < L) {
        int t = lane;
        float dv = cm_b3[n] + dotv<16>(cm_w3 + n * 64, s_d2 + t * 68);
        s_dd[t] = dv;
        if (t == idx)
          out[((size_t)b * T + idx) * 8 + n] = dv;
      }
      __syncthreads();
      // ---- cond_n(decoded rows 0..idx) -> emb history (read by self at
      // idx+1 and by node n+1 at its idx)
#pragma unroll 1
      for (int it = lane; it < L * 32; it += NT) {
        int t = it >> 5, k = it & 31;
        s_ch[t * 36 + k] =
            fmaxf(fmaf(s_dd[t], cond_w1[n * 32 + k], cond_b1[n * 32 + k]), 0.0f);
      }
      __syncthreads();
      if (lane < L * 8) {
        int t = lane >> 3, c = lane & 7;
        hist_own[idx * 64 + t * 8 + c] =
            cond_b2[n * 8 + c] + dotv<8>(cond_w2 + (size_t)(n * 8 + c) * 32, s_ch + t * 36);
      }
      __syncthreads();
    }
  }
}

extern "C" void kernel_launch(void* const* d_in, const int* in_sizes, int n_in,
                              void* d_out, int out_size, void* d_ws, size_t ws_size,
                              hipStream_t stream) {
  const float* z       = (const float*)d_in[0];
  const float* cond_w1 = (const float*)d_in[1];
  const float* cond_b1 = (const float*)d_in[2];
  const float* cond_w2 = (const float*)d_in[3];
  const float* cond_b2 = (const float*)d_in[4];
  const float* proj_w  = (const float*)d_in[5];
  const float* proj_b  = (const float*)d_in[6];
  const float* gpw     = (const float*)d_in[7];
  const float* gpb     = (const float*)d_in[8];
  const float* gru_wih = (const float*)d_in[9];
  const float* gru_whh = (const float*)d_in[10];
  const float* gru_bih = (const float*)d_in[11];
  const float* gru_bhh = (const float*)d_in[12];
  const float* cm_w1   = (const float*)d_in[13];
  const float* cm_b1   = (const float*)d_in[14];
  const float* cm_w2   = (const float*)d_in[15];
  const float* cm_b2   = (const float*)d_in[16];
  const float* cm_w3   = (const float*)d_in[17];
  const float* cm_b3   = (const float*)d_in[18];
  const int*   endw    = (const int*)d_in[19];
  float* out = (float*)d_out;

  int Btot = in_sizes[0] / (8 * 8 * 32);  // z: [8, B, 8, 32]

  tcm_kernel<<<Btot, NT, 0, stream>>>(
      z, cond_w1, cond_b1, cond_w2, cond_b2, proj_w, proj_b, gpw, gpb,
      gru_wih, gru_whh, gru_bih, gru_bhh, cm_w1, cm_b1, cm_w2, cm_b2,
      cm_w3, cm_b3, endw, out, Btot);
}

// Round 4
// 1061.689 us; speedup vs baseline: 3.4312x; 3.4312x over previous
//
#include <hip/hip_runtime.h>

// TemporalCausalMaps on MI355X (gfx950), round 7.
// Round-3 structure (1 wave/block, idx-outer, per-stage weight hoists —
// known-good 1196us, VGPR=128 no spills) + ILP attack on dependent FMA
// chains (the real bottleneck: ~2 waves/SIMD, 4cyc fma latency vs 2cyc
// issue needs ILP>=2; cm2 was a 64-deep single chain):
//  - every dot split into 2-4 accumulators
//  - gates/cm1/cm2 t-loops unrolled by 2 (independent t's -> ILP 4)
//  - half-split GRU recurrence (12-deep chains + shfl_xor(32), bias once)
//  - cond-net computed ONCE per decoded row into s_emb[8][8][8]
//    (cell (idx,n) writes rows 0..idx at end; (idx+1,n) reads self-emb,
//    (idx,n+1) reads pred-emb -- both valid under idx-outer/n-inner)
// Round-6 lesson: NO cross-stage register residency (210+ live VGPRs ->
// scratch spills -> 6.7GB HBM). Per-stage hoists only, <=80 live.

#define NT 64

__device__ __forceinline__ float sigm(float x) { return 1.0f / (1.0f + __expf(-x)); }
__device__ __forceinline__ float tanh_fast(float x) {
  x = fminf(15.0f, fmaxf(-15.0f, x));
  float e = __expf(2.0f * x);
  return (e - 1.0f) / (e + 1.0f);
}
__device__ __forceinline__ float leaky(float x) { return x >= 0.0f ? x : 0.01f * x; }

// 2-accumulator dot (N4 even): chain depth halves vs single-acc.
template <int N4>
__device__ __forceinline__ float dotv2(const float* __restrict__ w, const float* h) {
  const float4* w4 = reinterpret_cast<const float4*>(w);
  const float4* h4 = reinterpret_cast<const float4*>(h);
  float a0 = 0.0f, a1 = 0.0f;
#pragma unroll
  for (int i = 0; i < N4; i += 2) {
    float4 x0 = w4[i], y0 = h4[i];
    float4 x1 = w4[i + 1], y1 = h4[i + 1];
    a0 = fmaf(x0.x, y0.x, a0); a0 = fmaf(x0.y, y0.y, a0);
    a0 = fmaf(x0.z, y0.z, a0); a0 = fmaf(x0.w, y0.w, a0);
    a1 = fmaf(x1.x, y1.x, a1); a1 = fmaf(x1.y, y1.y, a1);
    a1 = fmaf(x1.z, y1.z, a1); a1 = fmaf(x1.w, y1.w, a1);
  }
  return a0 + a1;
}

// 4-accumulator dot (N4 % 4 == 0).
template <int N4>
__device__ __forceinline__ float dotv4(const float* __restrict__ w, const float* h) {
  const float4* w4 = reinterpret_cast<const float4*>(w);
  const float4* h4 = reinterpret_cast<const float4*>(h);
  float a0 = 0.0f, a1 = 0.0f, a2 = 0.0f, a3 = 0.0f;
#pragma unroll
  for (int i = 0; i < N4; i += 4) {
    float4 x0 = w4[i], y0 = h4[i];
    float4 x1 = w4[i + 1], y1 = h4[i + 1];
    float4 x2 = w4[i + 2], y2 = h4[i + 2];
    float4 x3 = w4[i + 3], y3 = h4[i + 3];
    a0 = fmaf(x0.x, y0.x, a0); a0 = fmaf(x0.y, y0.y, a0);
    a0 = fmaf(x0.z, y0.z, a0); a0 = fmaf(x0.w, y0.w, a0);
    a1 = fmaf(x1.x, y1.x, a1); a1 = fmaf(x1.y, y1.y, a1);
    a1 = fmaf(x1.z, y1.z, a1); a1 = fmaf(x1.w, y1.w, a1);
    a2 = fmaf(x2.x, y2.x, a2); a2 = fmaf(x2.y, y2.y, a2);
    a2 = fmaf(x2.z, y2.z, a2); a2 = fmaf(x2.w, y2.w, a2);
    a3 = fmaf(x3.x, y3.x, a3); a3 = fmaf(x3.y, y3.y, a3);
    a3 = fmaf(x3.z, y3.z, a3); a3 = fmaf(x3.w, y3.w, a3);
  }
  return (a0 + a1) + (a2 + a3);
}

// Input-gate stage: lane = gi row (0..63, rows 64..71 on lanes 0..7),
// t unrolled by 2 -> 4 independent 24-chains.
__device__ __forceinline__ void gates_stage(
    const float* __restrict__ wih, const float* __restrict__ bih,
    const float* srcp, float* s_gi, int L, int lane, int rowB) {
  float4 WA[6], WB[6];
  const float4* wa = reinterpret_cast<const float4*>(wih + (size_t)lane * 24);
  const float4* wb = reinterpret_cast<const float4*>(wih + (size_t)rowB * 24);
#pragma unroll
  for (int i = 0; i < 6; ++i) { WA[i] = wa[i]; WB[i] = wb[i]; }
  const float bA = bih[lane], bB = bih[rowB];
  int t = 0;
#pragma unroll 1
  for (; t + 1 < L; t += 2) {
    const float4* h0 = reinterpret_cast<const float4*>(srcp + t * 24);
    const float4* h1 = reinterpret_cast<const float4*>(srcp + t * 24 + 24);
    float a0 = bA, a1 = bA, c0 = bB, c1 = bB;
#pragma unroll
    for (int i = 0; i < 6; ++i) {
      float4 p = h0[i], q = h1[i], A = WA[i], Bv = WB[i];
      a0 = fmaf(A.x, p.x, a0); a0 = fmaf(A.y, p.y, a0);
      a0 = fmaf(A.z, p.z, a0); a0 = fmaf(A.w, p.w, a0);
      a1 = fmaf(A.x, q.x, a1); a1 = fmaf(A.y, q.y, a1);
      a1 = fmaf(A.z, q.z, a1); a1 = fmaf(A.w, q.w, a1);
      c0 = fmaf(Bv.x, p.x, c0); c0 = fmaf(Bv.y, p.y, c0);
      c0 = fmaf(Bv.z, p.z, c0); c0 = fmaf(Bv.w, p.w, c0);
      c1 = fmaf(Bv.x, q.x, c1); c1 = fmaf(Bv.y, q.y, c1);
      c1 = fmaf(Bv.z, q.z, c1); c1 = fmaf(Bv.w, q.w, c1);
    }
    s_gi[t * 72 + lane] = a0;
    s_gi[t * 72 + 72 + lane] = a1;
    if (lane < 8) {
      s_gi[t * 72 + 64 + lane] = c0;
      s_gi[t * 72 + 136 + lane] = c1;
    }
  }
  if (t < L) {
    const float4* h0 = reinterpret_cast<const float4*>(srcp + t * 24);
    float a0 = bA, c0 = bB;
#pragma unroll
    for (int i = 0; i < 6; ++i) {
      float4 p = h0[i], A = WA[i], Bv = WB[i];
      a0 = fmaf(A.x, p.x, a0); a0 = fmaf(A.y, p.y, a0);
      a0 = fmaf(A.z, p.z, a0); a0 = fmaf(A.w, p.w, a0);
      c0 = fmaf(Bv.x, p.x, c0); c0 = fmaf(Bv.y, p.y, c0);
      c0 = fmaf(Bv.z, p.z, c0); c0 = fmaf(Bv.w, p.w, c0);
    }
    s_gi[t * 72 + lane] = a0;
    if (lane < 8) s_gi[t * 72 + 64 + lane] = c0;
  }
}

// GRU hidden recurrence: half-split (lanes j and j+32 each take 12 of 24
// inputs, combine with shfl_xor(32), bias counted once on half 0).
// Single wave: no barriers needed inside (compiler orders intra-wave LDS).
__device__ __forceinline__ void rec_stage(
    const float* __restrict__ whh, const float* __restrict__ bhh,
    const float* s_gi, float* s_hid, float* s_y, int L, int lane, int jq, int half) {
  float4 Wr[3], Wz[3], Wn[3];
  const float4* wr = reinterpret_cast<const float4*>(whh + jq * 24 + half * 12);
  const float4* wz = reinterpret_cast<const float4*>(whh + (24 + jq) * 24 + half * 12);
  const float4* wn = reinterpret_cast<const float4*>(whh + (48 + jq) * 24 + half * 12);
#pragma unroll
  for (int i = 0; i < 3; ++i) { Wr[i] = wr[i]; Wz[i] = wz[i]; Wn[i] = wn[i]; }
  const float bR = half ? 0.0f : bhh[jq];
  const float bZ = half ? 0.0f : bhh[24 + jq];
  const float bN = half ? 0.0f : bhh[48 + jq];
  if (lane < 24) s_hid[lane] = 0.0f;
  int cur = 0;
#pragma unroll 1
  for (int t = 0; t < L; ++t) {
    const float4* hp = reinterpret_cast<const float4*>(s_hid + cur * 24 + half * 12);
    float gr = bR, gz = bZ, gn = bN;
#pragma unroll
    for (int i = 0; i < 3; ++i) {
      float4 hh = hp[i];
      gr = fmaf(Wr[i].x, hh.x, gr); gr = fmaf(Wr[i].y, hh.y, gr);
      gr = fmaf(Wr[i].z, hh.z, gr); gr = fmaf(Wr[i].w, hh.w, gr);
      gz = fmaf(Wz[i].x, hh.x, gz); gz = fmaf(Wz[i].y, hh.y, gz);
      gz = fmaf(Wz[i].z, hh.z, gz); gz = fmaf(Wz[i].w, hh.w, gz);
      gn = fmaf(Wn[i].x, hh.x, gn); gn = fmaf(Wn[i].y, hh.y, gn);
      gn = fmaf(Wn[i].z, hh.z, gn); gn = fmaf(Wn[i].w, hh.w, gn);
    }
    gr += __shfl_xor(gr, 32);
    gz += __shfl_xor(gz, 32);
    gn += __shfl_xor(gn, 32);
    const float* gi = s_gi + t * 72;
    float r   = sigm(gi[jq] + gr);
    float zg  = sigm(gi[24 + jq] + gz);
    float nn2 = tanh_fast(gi[48 + jq] + r * gn);
    float hold = s_hid[cur * 24 + jq];
    float hnew = fmaf(zg, hold - nn2, nn2);  // (1-z)*n + z*h
    if (lane < 24) {
      s_hid[(cur ^ 1) * 24 + lane] = hnew;
      s_y[t * 24 + lane] = hnew;
    }
    cur ^= 1;
  }
}

// LDS layout (floats), 16B-aligned segment starts. Total 3488 floats = 13952 B.
//  s_x   [8][48] @0      s_h  [8][24] @384    s_g   [8][24] @576
//  s_gi  [8][72] @768    s_y  [8][24] @1344   s_hid [2][24] @1536
//  s_d1  [8][68] @1584   s_d2 [8][68] @2128   s_dd  [16]    @2672
//  s_ch  [8][36] @2688   s_emb[8][8][8] @2976
__global__ __launch_bounds__(NT, 2) void tcm_kernel(
    const float* __restrict__ z,
    const float* __restrict__ cond_w1, const float* __restrict__ cond_b1,
    const float* __restrict__ cond_w2, const float* __restrict__ cond_b2,
    const float* __restrict__ proj_w, const float* __restrict__ proj_b,
    const float* __restrict__ gpw, const float* __restrict__ gpb,
    const float* __restrict__ gru_wih, const float* __restrict__ gru_whh,
    const float* __restrict__ gru_bih, const float* __restrict__ gru_bhh,
    const float* __restrict__ cm_w1, const float* __restrict__ cm_b1,
    const float* __restrict__ cm_w2, const float* __restrict__ cm_b2,
    const float* __restrict__ cm_w3, const float* __restrict__ cm_b3,
    const int* __restrict__ endw,
    float* __restrict__ out, int Btot) {
  __shared__ __align__(16) float lds[3488];
  float* s_x   = lds;
  float* s_h   = lds + 384;
  float* s_g   = lds + 576;
  float* s_gi  = lds + 768;
  float* s_y   = lds + 1344;
  float* s_hid = lds + 1536;
  float* s_d1  = lds + 1584;   // stride 68
  float* s_d2  = lds + 2128;   // stride 68
  float* s_dd  = lds + 2672;
  float* s_ch  = lds + 2688;   // stride 36
  float* s_emb = lds + 2976;   // [n][t][c] = n*64 + t*8 + c

  const int lane = threadIdx.x;
  const int b = blockIdx.x;
  const int T = endw[0];
  const int jm = lane & 31;
  const int half = lane >> 5;
  const int jq = jm < 24 ? jm : 0;
  const int rowB = 64 + (lane & 7);

#pragma unroll 1
  for (int idx = 0; idx < T; ++idx) {
    const int L = idx + 1;
#pragma unroll 1
    for (int n = 0; n < 8; ++n) {
      const float* wih0 = gru_wih + (size_t)(n * 2) * 1728;
      const float* wih1 = wih0 + 1728;
      const float* whh0 = gru_whh + (size_t)(n * 2) * 1728;
      const float* whh1 = whh0 + 1728;
      const float* bih0 = gru_bih + (n * 2) * 72;
      const float* bih1 = bih0 + 72;
      const float* bhh0 = gru_bhh + (n * 2) * 72;
      const float* bhh1 = bhh0 + 72;

      // ---- phase A: s_x = [z | emb_self | emb_pred]
      if (lane < L * 8) {
        const float4* z4 = reinterpret_cast<const float4*>(
            z + ((size_t)n * Btot + b) * 8 * 32);
        int t = lane >> 3, q = lane & 7;
        reinterpret_cast<float4*>(s_x)[t * 12 + q] = z4[t * 8 + q];
      }
#pragma unroll 1
      for (int it = lane; it < L * 16; it += NT) {
        int t = it >> 4, c = it & 15;
        float v = 0.0f;
        if (c < 8) {
          if (t < idx) v = s_emb[n * 64 + t * 8 + c];
        } else {
          if (n > 0 && idx > 0) v = s_emb[(n - 1) * 64 + t * 8 + (c - 8)];
        }
        s_x[t * 48 + 32 + c] = v;
      }
      __syncthreads();
      // ---- proj -> leaky
#pragma unroll 1
      for (int it = lane; it < L * 24; it += NT) {
        int t = it / 24, j = it - t * 24;
        float acc = proj_b[n * 24 + j] +
                    dotv2<12>(proj_w + (size_t)(n * 24 + j) * 48, s_x + t * 48);
        s_h[t * 24 + j] = leaky(acc);
      }
      __syncthreads();
      // ---- gru_proj
#pragma unroll 1
      for (int it = lane; it < L * 24; it += NT) {
        int t = it / 24, j = it - t * 24;
        s_g[t * 24 + j] = gpb[j] + dotv2<6>(gpw + j * 24, s_h + t * 24);
      }
      __syncthreads();
      // ---- GRU layer 0
      gates_stage(wih0, bih0, s_g, s_gi, L, lane, rowB);
      __syncthreads();
      rec_stage(whh0, bhh0, s_gi, s_hid, s_y, L, lane, jq, half);
      __syncthreads();
      // ---- GRU layer 1
      gates_stage(wih1, bih1, s_y, s_gi, L, lane, rowB);
      __syncthreads();
      rec_stage(whh1, bhh1, s_gi, s_hid, s_y, L, lane, jq, half);
      __syncthreads();
      // ---- cm1: lane = j, t unrolled by 2
      {
        float4 C1[6];
        const float4* p = reinterpret_cast<const float4*>(
            cm_w1 + (size_t)(n * 64 + lane) * 24);
#pragma unroll
        for (int i = 0; i < 6; ++i) C1[i] = p[i];
        const float bb = cm_b1[n * 64 + lane];
        int t = 0;
#pragma unroll 1
        for (; t + 1 < L; t += 2) {
          const float4* y0 = reinterpret_cast<const float4*>(s_y + t * 24);
          const float4* y1 = reinterpret_cast<const float4*>(s_y + t * 24 + 24);
          float a0 = bb, a1 = bb;
#pragma unroll
          for (int i = 0; i < 6; ++i) {
            float4 pp = y0[i], q = y1[i], W = C1[i];
            a0 = fmaf(W.x, pp.x, a0); a0 = fmaf(W.y, pp.y, a0);
            a0 = fmaf(W.z, pp.z, a0); a0 = fmaf(W.w, pp.w, a0);
            a1 = fmaf(W.x, q.x, a1); a1 = fmaf(W.y, q.y, a1);
            a1 = fmaf(W.z, q.z, a1); a1 = fmaf(W.w, q.w, a1);
          }
          s_d1[t * 68 + lane] = fmaxf(a0, 0.0f);
          s_d1[t * 68 + 68 + lane] = fmaxf(a1, 0.0f);
        }
        if (t < L) {
          float acc = bb;
          const float4* y0 = reinterpret_cast<const float4*>(s_y + t * 24);
#pragma unroll
          for (int i = 0; i < 6; ++i) {
            float4 pp = y0[i], W = C1[i];
            acc = fmaf(W.x, pp.x, acc); acc = fmaf(W.y, pp.y, acc);
            acc = fmaf(W.z, pp.z, acc); acc = fmaf(W.w, pp.w, acc);
          }
          s_d1[t * 68 + lane] = fmaxf(acc, 0.0f);
        }
      }
      __syncthreads();
      // ---- cm2: lane = j, t unrolled by 2, 2 accs per t
      {
        float4 C2[16];
        const float4* p = reinterpret_cast<const float4*>(
            cm_w2 + (size_t)(n * 64 + lane) * 64);
#pragma unroll
        for (int i = 0; i < 16; ++i) C2[i] = p[i];
        const float bb = cm_b2[n * 64 + lane];
        int t = 0;
#pragma unroll 1
        for (; t + 1 < L; t += 2) {
          const float4* d0 = reinterpret_cast<const float4*>(s_d1 + t * 68);
          const float4* d1 = reinterpret_cast<const float4*>(s_d1 + t * 68 + 68);
          float a0 = bb, a1 = 0.0f, c0 = bb, c1 = 0.0f;
#pragma unroll
          for (int i = 0; i < 16; i += 2) {
            float4 W0 = C2[i], W1 = C2[i + 1];
            float4 p0 = d0[i], p1 = d0[i + 1], q0 = d1[i], q1 = d1[i + 1];
            a0 = fmaf(W0.x, p0.x, a0); a0 = fmaf(W0.y, p0.y, a0);
            a0 = fmaf(W0.z, p0.z, a0); a0 = fmaf(W0.w, p0.w, a0);
            a1 = fmaf(W1.x, p1.x, a1); a1 = fmaf(W1.y, p1.y, a1);
            a1 = fmaf(W1.z, p1.z, a1); a1 = fmaf(W1.w, p1.w, a1);
            c0 = fmaf(W0.x, q0.x, c0); c0 = fmaf(W0.y, q0.y, c0);
            c0 = fmaf(W0.z, q0.z, c0); c0 = fmaf(W0.w, q0.w, c0);
            c1 = fmaf(W1.x, q1.x, c1); c1 = fmaf(W1.y, q1.y, c1);
            c1 = fmaf(W1.z, q1.z, c1); c1 = fmaf(W1.w, q1.w, c1);
          }
          s_d2[t * 68 + lane] = fmaxf(a0 + a1, 0.0f);
          s_d2[t * 68 + 68 + lane] = fmaxf(c0 + c1, 0.0f);
        }
        if (t < L) {
          const float4* d0 = reinterpret_cast<const float4*>(s_d1 + t * 68);
          float a0 = bb, a1 = 0.0f;
#pragma unroll
          for (int i = 0; i < 16; i += 2) {
            float4 W0 = C2[i], W1 = C2[i + 1];
            float4 p0 = d0[i], p1 = d0[i + 1];
            a0 = fmaf(W0.x, p0.x, a0); a0 = fmaf(W0.y, p0.y, a0);
            a0 = fmaf(W0.z, p0.z, a0); a0 = fmaf(W0.w, p0.w, a0);
            a1 = fmaf(W1.x, p1.x, a1); a1 = fmaf(W1.y, p1.y, a1);
            a1 = fmaf(W1.z, p1.z, a1); a1 = fmaf(W1.w, p1.w, a1);
          }
          s_d2[t * 68 + lane] = fmaxf(a0 + a1, 0.0f);
        }
      }
      __syncthreads();
      // ---- cm3 -> decoded row + emit
      if (lane < L) {
        int t = lane;
        float dv = cm_b3[n] + dotv4<16>(cm_w3 + n * 64, s_d2 + t * 68);
        s_dd[t] = dv;
        if (t == idx)
          out[((size_t)b * T + idx) * 8 + n] = dv;
      }
      __syncthreads();
      // ---- cond-net ONCE per decoded row -> s_emb[n]
#pragma unroll 1
      for (int it = lane; it < L * 32; it += NT) {
        int t = it >> 5, k = it & 31;
        s_ch[t * 36 + k] =
            fmaxf(fmaf(s_dd[t], cond_w1[n * 32 + k], cond_b1[n * 32 + k]), 0.0f);
      }
      __syncthreads();
      if (lane < L * 8) {
        int t = lane >> 3, c = lane & 7;
        s_emb[n * 64 + t * 8 + c] =
            cond_b2[n * 8 + c] +
            dotv2<8>(cond_w2 + (size_t)(n * 8 + c) * 32, s_ch + t * 36);
      }
      __syncthreads();
    }
  }
}

extern "C" void kernel_launch(void* const* d_in, const int* in_sizes, int n_in,
                              void* d_out, int out_size, void* d_ws, size_t ws_size,
                              hipStream_t stream) {
  const float* z       = (const float*)d_in[0];
  const float* cond_w1 = (const float*)d_in[1];
  const float* cond_b1 = (const float*)d_in[2];
  const float* cond_w2 = (const float*)d_in[3];
  const float* cond_b2 = (const float*)d_in[4];
  const float* proj_w  = (const float*)d_in[5];
  const float* proj_b  = (const float*)d_in[6];
  const float* gpw     = (const float*)d_in[7];
  const float* gpb     = (const float*)d_in[8];
  const float* gru_wih = (const float*)d_in[9];
  const float* gru_whh = (const float*)d_in[10];
  const float* gru_bih = (const float*)d_in[11];
  const float* gru_bhh = (const float*)d_in[12];
  const float* cm_w1   = (const float*)d_in[13];
  const float* cm_b1   = (const float*)d_in[14];
  const float* cm_w2   = (const float*)d_in[15];
  const float* cm_b2   = (const float*)d_in[16];
  const float* cm_w3   = (const float*)d_in[17];
  const float* cm_b3   = (const float*)d_in[18];
  const int*   endw    = (const int*)d_in[19];
  float* out = (float*)d_out;

  int Btot = in_sizes[0] / (8 * 8 * 32);  // z: [8, B, 8, 32]

  tcm_kernel<<<Btot, NT, 0, stream>>>(
      z, cond_w1, cond_b1, cond_w2, cond_b2, proj_w, proj_b, gpw, gpb,
      gru_wih, gru_whh, gru_bih, gru_bhh, cm_w1, cm_b1, cm_w2, cm_b2,
      cm_w3, cm_b3, endw, out, Btot);
}

// Round 5
// 1025.707 us; speedup vs baseline: 3.5515x; 1.0351x over previous
//
#include <hip/hip_runtime.h>

// TemporalCausalMaps on MI355X (gfx950), round 8.
// r7 structure (1 wave/block, idx-outer, ILP'd dots — 1062us) with the
// barrier-drain fix:
//  - Blocks are ONE wave => wave-synchronous. Every __syncthreads compiled
//    to "s_waitcnt vmcnt(0) lgkmcnt(0); s_barrier", draining ALL global
//    loads ~12x per cell x 64 cells => cross-stage weight prefetch was
//    impossible and each stage's weight fetch latency (~200-350cy L2) was
//    serially exposed. Replace with an LDS-only fence:
//        asm volatile("s_waitcnt lgkmcnt(0)":::"memory")
//    (cross-lane LDS ordering preserved: compiler memory fence + in-order
//    per-wave DS pipe; vmcnt stays counted => global prefetch survives).
//  - Reinstate r3's cross-stage weight prefetch: each stage's weights are
//    loaded (into regs) during the PREVIOUS stage's compute. Peak live
//    weight regs ~88 (cm1+cm2) — far below the r6 spill cliff.

#define NT 64
#define SYNC() asm volatile("s_waitcnt lgkmcnt(0)" ::: "memory")

__device__ __forceinline__ float sigm(float x) { return 1.0f / (1.0f + __expf(-x)); }
__device__ __forceinline__ float tanh_fast(float x) {
  x = fminf(15.0f, fmaxf(-15.0f, x));
  float e = __expf(2.0f * x);
  return (e - 1.0f) / (e + 1.0f);
}
__device__ __forceinline__ float leaky(float x) { return x >= 0.0f ? x : 0.01f * x; }

template <int N4>
__device__ __forceinline__ float dotv2(const float* __restrict__ w, const float* h) {
  const float4* w4 = reinterpret_cast<const float4*>(w);
  const float4* h4 = reinterpret_cast<const float4*>(h);
  float a0 = 0.0f, a1 = 0.0f;
#pragma unroll
  for (int i = 0; i < N4; i += 2) {
    float4 x0 = w4[i], y0 = h4[i];
    float4 x1 = w4[i + 1], y1 = h4[i + 1];
    a0 = fmaf(x0.x, y0.x, a0); a0 = fmaf(x0.y, y0.y, a0);
    a0 = fmaf(x0.z, y0.z, a0); a0 = fmaf(x0.w, y0.w, a0);
    a1 = fmaf(x1.x, y1.x, a1); a1 = fmaf(x1.y, y1.y, a1);
    a1 = fmaf(x1.z, y1.z, a1); a1 = fmaf(x1.w, y1.w, a1);
  }
  return a0 + a1;
}

template <int N4>
__device__ __forceinline__ float dotv4(const float* __restrict__ w, const float* h) {
  const float4* w4 = reinterpret_cast<const float4*>(w);
  const float4* h4 = reinterpret_cast<const float4*>(h);
  float a0 = 0.0f, a1 = 0.0f, a2 = 0.0f, a3 = 0.0f;
#pragma unroll
  for (int i = 0; i < N4; i += 4) {
    float4 x0 = w4[i], y0 = h4[i];
    float4 x1 = w4[i + 1], y1 = h4[i + 1];
    float4 x2 = w4[i + 2], y2 = h4[i + 2];
    float4 x3 = w4[i + 3], y3 = h4[i + 3];
    a0 = fmaf(x0.x, y0.x, a0); a0 = fmaf(x0.y, y0.y, a0);
    a0 = fmaf(x0.z, y0.z, a0); a0 = fmaf(x0.w, y0.w, a0);
    a1 = fmaf(x1.x, y1.x, a1); a1 = fmaf(x1.y, y1.y, a1);
    a1 = fmaf(x1.z, y1.z, a1); a1 = fmaf(x1.w, y1.w, a1);
    a2 = fmaf(x2.x, y2.x, a2); a2 = fmaf(x2.y, y2.y, a2);
    a2 = fmaf(x2.z, y2.z, a2); a2 = fmaf(x2.w, y2.w, a2);
    a3 = fmaf(x3.x, y3.x, a3); a3 = fmaf(x3.y, y3.y, a3);
    a3 = fmaf(x3.w, y3.w, a3); a3 = fmaf(x3.z, y3.z, a3);
  }
  return (a0 + a1) + (a2 + a3);
}

// ---- weight loaders (prefetch points) ----
__device__ __forceinline__ void load_gates_w(
    const float* __restrict__ wih, const float* __restrict__ bih,
    int lane, int rowB, float4 WA[6], float4 WB[6], float& bA, float& bB) {
  const float4* wa = reinterpret_cast<const float4*>(wih + (size_t)lane * 24);
  const float4* wb = reinterpret_cast<const float4*>(wih + (size_t)rowB * 24);
#pragma unroll
  for (int i = 0; i < 6; ++i) { WA[i] = wa[i]; WB[i] = wb[i]; }
  bA = bih[lane]; bB = bih[rowB];
}

__device__ __forceinline__ void load_rec_w(
    const float* __restrict__ whh, const float* __restrict__ bhh,
    int jq, int half, float4 Wr[3], float4 Wz[3], float4 Wn[3],
    float& bR, float& bZ, float& bN) {
  const float4* wr = reinterpret_cast<const float4*>(whh + jq * 24 + half * 12);
  const float4* wz = reinterpret_cast<const float4*>(whh + (24 + jq) * 24 + half * 12);
  const float4* wn = reinterpret_cast<const float4*>(whh + (48 + jq) * 24 + half * 12);
#pragma unroll
  for (int i = 0; i < 3; ++i) { Wr[i] = wr[i]; Wz[i] = wz[i]; Wn[i] = wn[i]; }
  bR = half ? 0.0f : bhh[jq];
  bZ = half ? 0.0f : bhh[24 + jq];
  bN = half ? 0.0f : bhh[48 + jq];
}

// ---- compute stages (weights already in regs) ----
__device__ __forceinline__ void gates_comp(
    const float4 WA[6], const float4 WB[6], float bA, float bB,
    const float* srcp, float* s_gi, int L, int lane) {
  int t = 0;
#pragma unroll 1
  for (; t + 1 < L; t += 2) {
    const float4* h0 = reinterpret_cast<const float4*>(srcp + t * 24);
    const float4* h1 = reinterpret_cast<const float4*>(srcp + t * 24 + 24);
    float a0 = bA, a1 = bA, c0 = bB, c1 = bB;
#pragma unroll
    for (int i = 0; i < 6; ++i) {
      float4 p = h0[i], q = h1[i], A = WA[i], Bv = WB[i];
      a0 = fmaf(A.x, p.x, a0); a0 = fmaf(A.y, p.y, a0);
      a0 = fmaf(A.z, p.z, a0); a0 = fmaf(A.w, p.w, a0);
      a1 = fmaf(A.x, q.x, a1); a1 = fmaf(A.y, q.y, a1);
      a1 = fmaf(A.z, q.z, a1); a1 = fmaf(A.w, q.w, a1);
      c0 = fmaf(Bv.x, p.x, c0); c0 = fmaf(Bv.y, p.y, c0);
      c0 = fmaf(Bv.z, p.z, c0); c0 = fmaf(Bv.w, p.w, c0);
      c1 = fmaf(Bv.x, q.x, c1); c1 = fmaf(Bv.y, q.y, c1);
      c1 = fmaf(Bv.z, q.z, c1); c1 = fmaf(Bv.w, q.w, c1);
    }
    s_gi[t * 72 + lane] = a0;
    s_gi[t * 72 + 72 + lane] = a1;
    if (lane < 8) {
      s_gi[t * 72 + 64 + lane] = c0;
      s_gi[t * 72 + 136 + lane] = c1;
    }
  }
  if (t < L) {
    const float4* h0 = reinterpret_cast<const float4*>(srcp + t * 24);
    float a0 = bA, c0 = bB;
#pragma unroll
    for (int i = 0; i < 6; ++i) {
      float4 p = h0[i], A = WA[i], Bv = WB[i];
      a0 = fmaf(A.x, p.x, a0); a0 = fmaf(A.y, p.y, a0);
      a0 = fmaf(A.z, p.z, a0); a0 = fmaf(A.w, p.w, a0);
      c0 = fmaf(Bv.x, p.x, c0); c0 = fmaf(Bv.y, p.y, c0);
      c0 = fmaf(Bv.z, p.z, c0); c0 = fmaf(Bv.w, p.w, c0);
    }
    s_gi[t * 72 + lane] = a0;
    if (lane < 8) s_gi[t * 72 + 64 + lane] = c0;
  }
}

__device__ __forceinline__ void rec_comp(
    const float4 Wr[3], const float4 Wz[3], const float4 Wn[3],
    float bR, float bZ, float bN,
    const float* s_gi, float* s_hid, float* s_y, int L, int lane, int jq, int half) {
  if (lane < 24) s_hid[lane] = 0.0f;
  int cur = 0;
#pragma unroll 1
  for (int t = 0; t < L; ++t) {
    const float4* hp = reinterpret_cast<const float4*>(s_hid + cur * 24 + half * 12);
    float gr = bR, gz = bZ, gn = bN;
#pragma unroll
    for (int i = 0; i < 3; ++i) {
      float4 hh = hp[i];
      gr = fmaf(Wr[i].x, hh.x, gr); gr = fmaf(Wr[i].y, hh.y, gr);
      gr = fmaf(Wr[i].z, hh.z, gr); gr = fmaf(Wr[i].w, hh.w, gr);
      gz = fmaf(Wz[i].x, hh.x, gz); gz = fmaf(Wz[i].y, hh.y, gz);
      gz = fmaf(Wz[i].z, hh.z, gz); gz = fmaf(Wz[i].w, hh.w, gz);
      gn = fmaf(Wn[i].x, hh.x, gn); gn = fmaf(Wn[i].y, hh.y, gn);
      gn = fmaf(Wn[i].z, hh.z, gn); gn = fmaf(Wn[i].w, hh.w, gn);
    }
    gr += __shfl_xor(gr, 32);
    gz += __shfl_xor(gz, 32);
    gn += __shfl_xor(gn, 32);
    const float* gi = s_gi + t * 72;
    float r   = sigm(gi[jq] + gr);
    float zg  = sigm(gi[24 + jq] + gz);
    float nn2 = tanh_fast(gi[48 + jq] + r * gn);
    float hold = s_hid[cur * 24 + jq];
    float hnew = fmaf(zg, hold - nn2, nn2);  // (1-z)*n + z*h
    if (lane < 24) {
      s_hid[(cur ^ 1) * 24 + lane] = hnew;
      s_y[t * 24 + lane] = hnew;
    }
    cur ^= 1;
  }
}

// LDS layout (floats). Total 3488 floats = 13952 B.
//  s_x   [8][48] @0      s_h  [8][24] @384    s_g   [8][24] @576
//  s_gi  [8][72] @768    s_y  [8][24] @1344   s_hid [2][24] @1536
//  s_d1  [8][68] @1584   s_d2 [8][68] @2128   s_dd  [16]    @2672
//  s_ch  [8][36] @2688   s_emb[8][8][8] @2976
__global__ __launch_bounds__(NT, 2) void tcm_kernel(
    const float* __restrict__ z,
    const float* __restrict__ cond_w1, const float* __restrict__ cond_b1,
    const float* __restrict__ cond_w2, const float* __restrict__ cond_b2,
    const float* __restrict__ proj_w, const float* __restrict__ proj_b,
    const float* __restrict__ gpw, const float* __restrict__ gpb,
    const float* __restrict__ gru_wih, const float* __restrict__ gru_whh,
    const float* __restrict__ gru_bih, const float* __restrict__ gru_bhh,
    const float* __restrict__ cm_w1, const float* __restrict__ cm_b1,
    const float* __restrict__ cm_w2, const float* __restrict__ cm_b2,
    const float* __restrict__ cm_w3, const float* __restrict__ cm_b3,
    const int* __restrict__ endw,
    float* __restrict__ out, int Btot) {
  __shared__ __align__(16) float lds[3488];
  float* s_x   = lds;
  float* s_h   = lds + 384;
  float* s_g   = lds + 576;
  float* s_gi  = lds + 768;
  float* s_y   = lds + 1344;
  float* s_hid = lds + 1536;
  float* s_d1  = lds + 1584;   // stride 68
  float* s_d2  = lds + 2128;   // stride 68
  float* s_dd  = lds + 2672;
  float* s_ch  = lds + 2688;   // stride 36
  float* s_emb = lds + 2976;   // [n][t][c] = n*64 + t*8 + c

  const int lane = threadIdx.x;
  const int b = blockIdx.x;
  const int T = endw[0];
  const int jm = lane & 31;
  const int half = lane >> 5;
  const int jq = jm < 24 ? jm : 0;
  const int rowB = 64 + (lane & 7);

#pragma unroll 1
  for (int idx = 0; idx < T; ++idx) {
    const int L = idx + 1;
#pragma unroll 1
    for (int n = 0; n < 8; ++n) {
      const float* wih0 = gru_wih + (size_t)(n * 2) * 1728;
      const float* wih1 = wih0 + 1728;
      const float* whh0 = gru_whh + (size_t)(n * 2) * 1728;
      const float* whh1 = whh0 + 1728;
      const float* bih0 = gru_bih + (n * 2) * 72;
      const float* bih1 = bih0 + 72;
      const float* bhh0 = gru_bhh + (n * 2) * 72;
      const float* bhh1 = bhh0 + 72;

      // prefetch gates-L0 weights (used after proj/gproj)
      float4 WA[6], WB[6]; float bA, bB;
      load_gates_w(wih0, bih0, lane, rowB, WA, WB, bA, bB);

      // ---- phase A: s_x = [z | emb_self | emb_pred]
      if (lane < L * 8) {
        const float4* z4 = reinterpret_cast<const float4*>(
            z + ((size_t)n * Btot + b) * 8 * 32);
        int t = lane >> 3, q = lane & 7;
        reinterpret_cast<float4*>(s_x)[t * 12 + q] = z4[t * 8 + q];
      }
#pragma unroll 1
      for (int it = lane; it < L * 16; it += NT) {
        int t = it >> 4, c = it & 15;
        float v = 0.0f;
        if (c < 8) {
          if (t < idx) v = s_emb[n * 64 + t * 8 + c];
        } else {
          if (n > 0 && idx > 0) v = s_emb[(n - 1) * 64 + t * 8 + (c - 8)];
        }
        s_x[t * 48 + 32 + c] = v;
      }
      SYNC();
      // ---- proj -> leaky
#pragma unroll 1
      for (int it = lane; it < L * 24; it += NT) {
        int t = it / 24, j = it - t * 24;
        float acc = proj_b[n * 24 + j] +
                    dotv2<12>(proj_w + (size_t)(n * 24 + j) * 48, s_x + t * 48);
        s_h[t * 24 + j] = leaky(acc);
      }
      SYNC();
      // ---- gru_proj
#pragma unroll 1
      for (int it = lane; it < L * 24; it += NT) {
        int t = it / 24, j = it - t * 24;
        s_g[t * 24 + j] = gpb[j] + dotv2<6>(gpw + j * 24, s_h + t * 24);
      }
      SYNC();
      // prefetch rec-L0 weights (in flight during gates L0)
      float4 Wr[3], Wz[3], Wn[3]; float bR, bZ, bN;
      load_rec_w(whh0, bhh0, jq, half, Wr, Wz, Wn, bR, bZ, bN);
      // ---- gates L0
      gates_comp(WA, WB, bA, bB, s_g, s_gi, L, lane);
      SYNC();
      // prefetch gates-L1 weights (in flight during rec L0)
      float4 WA1[6], WB1[6]; float bA1, bB1;
      load_gates_w(wih1, bih1, lane, rowB, WA1, WB1, bA1, bB1);
      // ---- rec L0 -> s_y
      rec_comp(Wr, Wz, Wn, bR, bZ, bN, s_gi, s_hid, s_y, L, lane, jq, half);
      SYNC();
      // prefetch rec-L1 weights (in flight during gates L1)
      float4 Wr1[3], Wz1[3], Wn1[3]; float bR1, bZ1, bN1;
      load_rec_w(whh1, bhh1, jq, half, Wr1, Wz1, Wn1, bR1, bZ1, bN1);
      // ---- gates L1
      gates_comp(WA1, WB1, bA1, bB1, s_y, s_gi, L, lane);
      SYNC();
      // prefetch cm1 row (in flight during rec L1)
      float4 C1[6];
      {
        const float4* p = reinterpret_cast<const float4*>(
            cm_w1 + (size_t)(n * 64 + lane) * 24);
#pragma unroll
        for (int i = 0; i < 6; ++i) C1[i] = p[i];
      }
      const float c1b = cm_b1[n * 64 + lane];
      // ---- rec L1 -> s_y
      rec_comp(Wr1, Wz1, Wn1, bR1, bZ1, bN1, s_gi, s_hid, s_y, L, lane, jq, half);
      SYNC();
      // prefetch cm2 row (in flight during cm1)
      float4 C2[16];
      {
        const float4* p = reinterpret_cast<const float4*>(
            cm_w2 + (size_t)(n * 64 + lane) * 64);
#pragma unroll
        for (int i = 0; i < 16; ++i) C2[i] = p[i];
      }
      const float c2b = cm_b2[n * 64 + lane];
      // ---- cm1: lane = j, t unrolled by 2
      {
        int t = 0;
#pragma unroll 1
        for (; t + 1 < L; t += 2) {
          const float4* y0 = reinterpret_cast<const float4*>(s_y + t * 24);
          const float4* y1 = reinterpret_cast<const float4*>(s_y + t * 24 + 24);
          float a0 = c1b, a1 = c1b;
#pragma unroll
          for (int i = 0; i < 6; ++i) {
            float4 pp = y0[i], q = y1[i], W = C1[i];
            a0 = fmaf(W.x, pp.x, a0); a0 = fmaf(W.y, pp.y, a0);
            a0 = fmaf(W.z, pp.z, a0); a0 = fmaf(W.w, pp.w, a0);
            a1 = fmaf(W.x, q.x, a1); a1 = fmaf(W.y, q.y, a1);
            a1 = fmaf(W.z, q.z, a1); a1 = fmaf(W.w, q.w, a1);
          }
          s_d1[t * 68 + lane] = fmaxf(a0, 0.0f);
          s_d1[t * 68 + 68 + lane] = fmaxf(a1, 0.0f);
        }
        if (t < L) {
          float acc = c1b;
          const float4* y0 = reinterpret_cast<const float4*>(s_y + t * 24);
#pragma unroll
          for (int i = 0; i < 6; ++i) {
            float4 pp = y0[i], W = C1[i];
            acc = fmaf(W.x, pp.x, acc); acc = fmaf(W.y, pp.y, acc);
            acc = fmaf(W.z, pp.z, acc); acc = fmaf(W.w, pp.w, acc);
          }
          s_d1[t * 68 + lane] = fmaxf(acc, 0.0f);
        }
      }
      SYNC();
      // ---- cm2: lane = j, t unrolled by 2, 2 accs per t
      {
        int t = 0;
#pragma unroll 1
        for (; t + 1 < L; t += 2) {
          const float4* d0 = reinterpret_cast<const float4*>(s_d1 + t * 68);
          const float4* d1 = reinterpret_cast<const float4*>(s_d1 + t * 68 + 68);
          float a0 = c2b, a1 = 0.0f, c0 = c2b, c1 = 0.0f;
#pragma unroll
          for (int i = 0; i < 16; i += 2) {
            float4 W0 = C2[i], W1 = C2[i + 1];
            float4 p0 = d0[i], p1 = d0[i + 1], q0 = d1[i], q1 = d1[i + 1];
            a0 = fmaf(W0.x, p0.x, a0); a0 = fmaf(W0.y, p0.y, a0);
            a0 = fmaf(W0.z, p0.z, a0); a0 = fmaf(W0.w, p0.w, a0);
            a1 = fmaf(W1.x, p1.x, a1); a1 = fmaf(W1.y, p1.y, a1);
            a1 = fmaf(W1.z, p1.z, a1); a1 = fmaf(W1.w, p1.w, a1);
            c0 = fmaf(W0.x, q0.x, c0); c0 = fmaf(W0.y, q0.y, c0);
            c0 = fmaf(W0.z, q0.z, c0); c0 = fmaf(W0.w, q0.w, c0);
            c1 = fmaf(W1.x, q1.x, c1); c1 = fmaf(W1.y, q1.y, c1);
            c1 = fmaf(W1.z, q1.z, c1); c1 = fmaf(W1.w, q1.w, c1);
          }
          s_d2[t * 68 + lane] = fmaxf(a0 + a1, 0.0f);
          s_d2[t * 68 + 68 + lane] = fmaxf(c0 + c1, 0.0f);
        }
        if (t < L) {
          const float4* d0 = reinterpret_cast<const float4*>(s_d1 + t * 68);
          float a0 = c2b, a1 = 0.0f;
#pragma unroll
          for (int i = 0; i < 16; i += 2) {
            float4 W0 = C2[i], W1 = C2[i + 1];
            float4 p0 = d0[i], p1 = d0[i + 1];
            a0 = fmaf(W0.x, p0.x, a0); a0 = fmaf(W0.y, p0.y, a0);
            a0 = fmaf(W0.z, p0.z, a0); a0 = fmaf(W0.w, p0.w, a0);
            a1 = fmaf(W1.x, p1.x, a1); a1 = fmaf(W1.y, p1.y, a1);
            a1 = fmaf(W1.z, p1.z, a1); a1 = fmaf(W1.w, p1.w, a1);
          }
          s_d2[t * 68 + lane] = fmaxf(a0 + a1, 0.0f);
        }
      }
      SYNC();
      // ---- cm3 -> decoded row + emit
      if (lane < L) {
        int t = lane;
        float dv = cm_b3[n] + dotv4<16>(cm_w3 + n * 64, s_d2 + t * 68);
        s_dd[t] = dv;
        if (t == idx)
          out[((size_t)b * T + idx) * 8 + n] = dv;
      }
      SYNC();
      // ---- cond-net ONCE per decoded row -> s_emb[n]
#pragma unroll 1
      for (int it = lane; it < L * 32; it += NT) {
        int t = it >> 5, k = it & 31;
        s_ch[t * 36 + k] =
            fmaxf(fmaf(s_dd[t], cond_w1[n * 32 + k], cond_b1[n * 32 + k]), 0.0f);
      }
      SYNC();
      if (lane < L * 8) {
        int t = lane >> 3, c = lane & 7;
        s_emb[n * 64 + t * 8 + c] =
            cond_b2[n * 8 + c] +
            dotv2<8>(cond_w2 + (size_t)(n * 8 + c) * 32, s_ch + t * 36);
      }
      SYNC();
    }
  }
}

extern "C" void kernel_launch(void* const* d_in, const int* in_sizes, int n_in,
                              void* d_out, int out_size, void* d_ws, size_t ws_size,
                              hipStream_t stream) {
  const float* z       = (const float*)d_in[0];
  const float* cond_w1 = (const float*)d_in[1];
  const float* cond_b1 = (const float*)d_in[2];
  const float* cond_w2 = (const float*)d_in[3];
  const float* cond_b2 = (const float*)d_in[4];
  const float* proj_w  = (const float*)d_in[5];
  const float* proj_b  = (const float*)d_in[6];
  const float* gpw     = (const float*)d_in[7];
  const float* gpb     = (const float*)d_in[8];
  const float* gru_wih = (const float*)d_in[9];
  const float* gru_whh = (const float*)d_in[10];
  const float* gru_bih = (const float*)d_in[11];
  const float* gru_bhh = (const float*)d_in[12];
  const float* cm_w1   = (const float*)d_in[13];
  const float* cm_b1   = (const float*)d_in[14];
  const float* cm_w2   = (const float*)d_in[15];
  const float* cm_b2   = (const float*)d_in[16];
  const float* cm_w3   = (const float*)d_in[17];
  const float* cm_b3   = (const float*)d_in[18];
  const int*   endw    = (const int*)d_in[19];
  float* out = (float*)d_out;

  int Btot = in_sizes[0] / (8 * 8 * 32);  // z: [8, B, 8, 32]

  tcm_kernel<<<Btot, NT, 0, stream>>>(
      z, cond_w1, cond_b1, cond_w2, cond_b2, proj_w, proj_b, gpw, gpb,
      gru_wih, gru_whh, gru_bih, gru_bhh, cm_w1, cm_b1, cm_w2, cm_b2,
      cm_w3, cm_b3, endw, out, Btot);
}